// Round 12
// baseline (3407.582 us; speedup 1.0000x reference)
//
#include <hip/hip_runtime.h>
#include <cstdint>
#include <cstddef>

// BottomUpNet: N=8192 rows independent; K=16 sequential steps.
// R12: B-weights pre-packed into exact MFMA B-operand fragment order and
// loaded global->VGPR directly (coalesced 1KB/wave, L2-resident) — no B LDS
// staging, no B LDS reads (R11 counters: LDS ~39k cyc/CU incl 13k conflicts
// vs MFMA 35k; 4 of 6 frag reads were B). A stays via LDS (BK=64, swizzle).
// m-chain: 2 MFMAs (weights fp32-exact hi/lo, activations fp16) — R11 WIN,
// absmax pinned at 1.192e-7. h-chain: 1 MFMA. Bit-identical math to R11.
// Packed layout: PB[n32][k16][(hi,lo)][lane][e], lane=(col&31)+32*((k>>3)&1),
// e=k&7 -> matches B-frag read B'[n=l31][k=l5*8+e] per 16-k tile.

typedef _Float16 f16x8 __attribute__((ext_vector_type(8)));
typedef float f32x16 __attribute__((ext_vector_type(16)));

__device__ __forceinline__ void gload16(const void* g, void* l) {
  // async global->LDS, 16B/lane, LDS dest = wave-uniform base + lane*16
  __builtin_amdgcn_global_load_lds(
      (__attribute__((address_space(1))) void*)const_cast<void*>(g),
      (__attribute__((address_space(3))) void*)l,
      16, 0, 0);
}

// ---- m-GEMM: C = relu(A@B^T + bias); A fp16 hi via LDS; B packed hi/lo
// global-direct (2 MFMAs). Tile 128x128, BK=64, 256 thr (4 waves, 64x64 each).
__global__ __launch_bounds__(256, 3)
void gemm_m_kernel(const _Float16* __restrict__ AH0, int ldA0,
                   const _Float16* __restrict__ AH1, int ldA1,
                   int kcut, int Ktot,
                   const _Float16* __restrict__ PB,   // packed [n32][k16][2][512]
                   const float* __restrict__ bias,
                   _Float16* __restrict__ CH, int ldC)
{
  __shared__ _Float16 sAh[128 * 64];

  const int lane = threadIdx.x & 63;
  const int wave = threadIdx.x >> 6;
  const int wm = (wave >> 1) * 64, wn = (wave & 1) * 64;
  const int mBase = blockIdx.x * 128, nBase = blockIdx.y * 128;

  // A staging: 8 rows/chunk (128 B rows), 8 lanes/row; seg swizz = ^(row&7)
  const int lr = lane >> 3;
  const int lcs8 = ((lane & 7) ^ lr) * 8;
  const int l31 = lane & 31, l5 = lane >> 5;
  const int fswz = l31 & 7;

  const int Kt16 = Ktot >> 4;
  const int n32b = (nBase + wn) >> 5;                // +j for j-tile
  const _Float16* pb0 = PB + ((size_t)(n32b)*Kt16) * 1024 + lane * 8;
  const _Float16* pb1 = PB + ((size_t)(n32b + 1) * Kt16) * 1024 + lane * 8;

  f32x16 acc[2][2];
#pragma unroll
  for (int i = 0; i < 2; ++i)
#pragma unroll
    for (int j = 0; j < 2; ++j)
      acc[i][j] = (f32x16)0.0f;

  for (int kt = 0; kt < Ktot; kt += 64) {
    const _Float16* aH; int pA, kl;
    if (kt < kcut) { aH = AH0; pA = ldA0; kl = kt; }
    else           { aH = AH1; pA = ldA1; kl = kt - kcut; }

#pragma unroll
    for (int cc = 0; cc < 4; ++cc) {
      const int c = wave * 4 + cc;                  // chunk 0..15, 8 rows each
      const int arow = mBase + c * 8 + lr;
      gload16(aH + (size_t)arow * pA + kl + lcs8, &sAh[c * 512]);
    }
    __syncthreads();

#pragma unroll
    for (int kh = 0; kh < 4; ++kh) {                // four K=16 MFMAs per BK=64
      const int k16 = (kt >> 4) + kh;
      const int ko = ((kh * 2 + l5) ^ fswz) * 8;    // swizzled A seg (0..7)
      f16x8 ah[2], bh[2], bl[2];
#pragma unroll
      for (int i = 0; i < 2; ++i)
        ah[i] = *(const f16x8*)&sAh[(wm + i * 32 + l31) * 64 + ko];
      bh[0] = *(const f16x8*)(pb0 + (size_t)k16 * 1024);
      bl[0] = *(const f16x8*)(pb0 + (size_t)k16 * 1024 + 512);
      bh[1] = *(const f16x8*)(pb1 + (size_t)k16 * 1024);
      bl[1] = *(const f16x8*)(pb1 + (size_t)k16 * 1024 + 512);
#pragma unroll
      for (int i = 0; i < 2; ++i)
#pragma unroll
        for (int j = 0; j < 2; ++j) {
          acc[i][j] = __builtin_amdgcn_mfma_f32_32x32x16_f16(ah[i], bl[j], acc[i][j], 0, 0, 0);
          acc[i][j] = __builtin_amdgcn_mfma_f32_32x32x16_f16(ah[i], bh[j], acc[i][j], 0, 0, 0);
        }
    }
    __syncthreads();
  }

  float bv[2];
#pragma unroll
  for (int j = 0; j < 2; ++j) bv[j] = bias[nBase + wn + j * 32 + l31];
#pragma unroll
  for (int i = 0; i < 2; ++i)
#pragma unroll
    for (int j = 0; j < 2; ++j)
#pragma unroll
      for (int r = 0; r < 16; ++r) {
        const int row = mBase + wm + i * 32 + (r & 3) + 8 * (r >> 2) + 4 * l5;
        const int col = nBase + wn + j * 32 + l31;
        float v = fmaxf(acc[i][j][r] + bv[j], 0.0f);
        CH[(size_t)row * ldC + col] = (_Float16)v;
      }
}

// ---- h-GEMM (hi-only, 1 MFMA): C = relu(A@B^T + bias) fp16 out,
// or fused-pred mode (sacc != null): sacc[row] += sum_col relu(.)*w3[col]
__global__ __launch_bounds__(256, 3)
void gemm_h_kernel(const _Float16* __restrict__ A0, int ldA0,
                   const _Float16* __restrict__ A1, int ldA1,
                   int kcut, int Ktot,
                   const _Float16* __restrict__ PB,   // packed [n32][k16][512]
                   const float* __restrict__ bias,
                   _Float16* __restrict__ C, int ldC,
                   const float* __restrict__ w3, float* __restrict__ sacc)
{
  __shared__ _Float16 sAh[128 * 64];

  const int lane = threadIdx.x & 63;
  const int wave = threadIdx.x >> 6;
  const int wm = (wave >> 1) * 64, wn = (wave & 1) * 64;
  const int mBase = blockIdx.x * 128, nBase = blockIdx.y * 128;

  const int lr = lane >> 3;
  const int lcs8 = ((lane & 7) ^ lr) * 8;
  const int l31 = lane & 31, l5 = lane >> 5;
  const int fswz = l31 & 7;

  const int Kt16 = Ktot >> 4;
  const int n32b = (nBase + wn) >> 5;
  const _Float16* pb0 = PB + ((size_t)(n32b)*Kt16) * 512 + lane * 8;
  const _Float16* pb1 = PB + ((size_t)(n32b + 1) * Kt16) * 512 + lane * 8;

  f32x16 acc[2][2];
#pragma unroll
  for (int i = 0; i < 2; ++i)
#pragma unroll
    for (int j = 0; j < 2; ++j)
      acc[i][j] = (f32x16)0.0f;

  for (int kt = 0; kt < Ktot; kt += 64) {
    const _Float16* aH; int pA, kl;
    if (kt < kcut) { aH = A0; pA = ldA0; kl = kt; }
    else           { aH = A1; pA = ldA1; kl = kt - kcut; }

#pragma unroll
    for (int cc = 0; cc < 4; ++cc) {
      const int c = wave * 4 + cc;
      const int arow = mBase + c * 8 + lr;
      gload16(aH + (size_t)arow * pA + kl + lcs8, &sAh[c * 512]);
    }
    __syncthreads();

#pragma unroll
    for (int kh = 0; kh < 4; ++kh) {
      const int k16 = (kt >> 4) + kh;
      const int ko = ((kh * 2 + l5) ^ fswz) * 8;
      f16x8 ah[2], bh[2];
#pragma unroll
      for (int i = 0; i < 2; ++i)
        ah[i] = *(const f16x8*)&sAh[(wm + i * 32 + l31) * 64 + ko];
      bh[0] = *(const f16x8*)(pb0 + (size_t)k16 * 512);
      bh[1] = *(const f16x8*)(pb1 + (size_t)k16 * 512);
#pragma unroll
      for (int i = 0; i < 2; ++i)
#pragma unroll
        for (int j = 0; j < 2; ++j)
          acc[i][j] = __builtin_amdgcn_mfma_f32_32x32x16_f16(ah[i], bh[j], acc[i][j], 0, 0, 0);
    }
    __syncthreads();
  }

  float bv[2], w3v[2];
#pragma unroll
  for (int j = 0; j < 2; ++j) {
    const int col = nBase + wn + j * 32 + l31;
    bv[j] = bias[col];
    w3v[j] = sacc ? w3[col] : 0.0f;
  }

  if (sacc) {
#pragma unroll
    for (int i = 0; i < 2; ++i)
#pragma unroll
      for (int r = 0; r < 16; ++r) {
        float pr = 0.0f;
#pragma unroll
        for (int j = 0; j < 2; ++j)
          pr += fmaxf(acc[i][j][r] + bv[j], 0.0f) * w3v[j];
        pr += __shfl_xor(pr, 1);
        pr += __shfl_xor(pr, 2);
        pr += __shfl_xor(pr, 4);
        pr += __shfl_xor(pr, 8);
        pr += __shfl_xor(pr, 16);
        if (l31 == 0)
          atomicAdd(&sacc[mBase + wm + i * 32 + (r & 3) + 8 * (r >> 2) + 4 * l5], pr);
      }
  } else {
#pragma unroll
    for (int i = 0; i < 2; ++i)
#pragma unroll
      for (int j = 0; j < 2; ++j)
#pragma unroll
        for (int r = 0; r < 16; ++r) {
          const int row = mBase + wm + i * 32 + (r & 3) + 8 * (r >> 2) + 4 * l5;
          const int col = nBase + wn + j * 32 + l31;
          float v = fmaxf(acc[i][j][r] + bv[j], 0.0f);
          C[(size_t)row * ldC + col] = (_Float16)v;
        }
  }
}

// W (K x N fp32) -> packed B-fragment layout.
// tid -> (n32, k16, lane, e); col=n32*32+(lane&31), k=k16*16+(lane>>5)*8+e.
// withLo: chunk pair [hi 512][lo 512] (stride 1024), else hi only (512).
__global__ void wconv_pack_kernel(const float* __restrict__ W, int K, int N,
                                  _Float16* __restrict__ out, int withLo) {
  int tid = blockIdx.x * 256 + threadIdx.x;
  if (tid >= K * N) return;
  const int Kt16 = K >> 4;
  int e = tid & 7;
  int lane = (tid >> 3) & 63;
  int k16 = (tid >> 9) % Kt16;
  int n32 = (tid >> 9) / Kt16;
  int col = (n32 << 5) + (lane & 31);
  int k = (k16 << 4) + ((lane >> 5) << 3) + e;
  float v = W[(size_t)k * N + col];
  _Float16 h = (_Float16)v;
  size_t base = ((size_t)(n32 * Kt16 + k16)) * (withLo ? 1024 : 512) + lane * 8 + e;
  out[base] = h;
  if (withLo) out[base + 512] = (_Float16)(v - (float)h);
}

__global__ void init_summary_kernel(const float* __restrict__ agg,
                                    _Float16* __restrict__ sH,
                                    float* __restrict__ sacc) {
  int idx = blockIdx.x * 256 + threadIdx.x;   // 8192*1024
  sH[idx] = (_Float16)agg[idx & 1023];
  if (idx < 8192) sacc[idx] = 0.0f;
}

// towers [n][k][f] fp32 -> towAll [k][n][f] fp16 hi (all 16 slices)
__global__ void tow_conv_all_kernel(const float* __restrict__ towers,
                                    _Float16* __restrict__ oH) {
  size_t idx = (size_t)blockIdx.x * 256 + threadIdx.x;  // (k*8192+n)*64+f
  int f = idx & 63;
  int n = (int)((idx >> 6) & 8191);
  int k = (int)(idx >> 19);
  oH[idx] = (_Float16)towers[((size_t)n * 16 + k) * 64 + f];
}

// pred = sigmoid(sacc + Ob3); out *= pred; re-zero sacc for next step
__global__ void pred_final_kernel(float* __restrict__ sacc, const float* __restrict__ b3,
                                  float* __restrict__ out, int step) {
  int row = blockIdx.x * 256 + threadIdx.x;   // 8192
  float p = 1.0f / (1.0f + expf(-(sacc[row] + b3[0])));
  out[row] = (step == 0) ? p : out[row] * p;
  sacc[row] = 0.0f;
}

extern "C" void kernel_launch(void* const* d_in, const int* in_sizes, int n_in,
                              void* d_out, int out_size, void* d_ws, size_t ws_size,
                              hipStream_t stream) {
  const float* towers = (const float*)d_in[0];
  const float* agg    = (const float*)d_in[1];
  const float* MW1 = (const float*)d_in[2];
  const float* Mb1 = (const float*)d_in[3];
  const float* MW2 = (const float*)d_in[4];
  const float* Mb2 = (const float*)d_in[5];
  const float* MW3 = (const float*)d_in[6];
  const float* Mb3 = (const float*)d_in[7];
  const float* OW1 = (const float*)d_in[8];
  const float* Ob1 = (const float*)d_in[9];
  const float* OW2 = (const float*)d_in[10];
  const float* Ob2 = (const float*)d_in[11];
  const float* OW3 = (const float*)d_in[12];
  const float* Ob3 = (const float*)d_in[13];
  float* out = (float*)d_out;

  // ws layout (~102 MiB)
  _Float16* p = (_Float16*)d_ws;
  _Float16* MW1p = p; p += (size_t)32 * 68 * 1024;   // hi/lo pairs
  _Float16* OW1p = p; p += (size_t)32 * 68 * 512;    // hi only
  _Float16* MW2p = p; p += (size_t)32 * 64 * 1024;
  _Float16* OW2p = p; p += (size_t)32 * 64 * 512;
  _Float16* MW3p = p; p += (size_t)32 * 64 * 1024;
  _Float16* sumH = p; p += (size_t)8192 * 1024;
  _Float16* m1H  = p; p += (size_t)8192 * 1024;
  _Float16* h1   = p; p += (size_t)8192 * 1024;
  _Float16* m2H  = p; p += (size_t)8192 * 1024;
  _Float16* towAllH = p; p += (size_t)16 * 8192 * 64;
  float* sacc = (float*)p;

  // per-call setup: pack weights into fragment layout, convert towers, init
  {
    int tot = 1088 * 1024;
    wconv_pack_kernel<<<dim3((tot + 255) / 256), dim3(256), 0, stream>>>(MW1, 1088, 1024, MW1p, 1);
    wconv_pack_kernel<<<dim3((tot + 255) / 256), dim3(256), 0, stream>>>(OW1, 1088, 1024, OW1p, 0);
    tot = 1024 * 1024;
    wconv_pack_kernel<<<dim3((tot + 255) / 256), dim3(256), 0, stream>>>(MW2, 1024, 1024, MW2p, 1);
    wconv_pack_kernel<<<dim3((tot + 255) / 256), dim3(256), 0, stream>>>(OW2, 1024, 1024, OW2p, 0);
    wconv_pack_kernel<<<dim3((tot + 255) / 256), dim3(256), 0, stream>>>(MW3, 1024, 1024, MW3p, 1);
    init_summary_kernel<<<dim3(32768), dim3(256), 0, stream>>>(agg, sumH, sacc);
    tow_conv_all_kernel<<<dim3(32768), dim3(256), 0, stream>>>(towers, towAllH);
  }

  const dim3 G(64, 8), B256(256);   // 128x128 tiles over 8192x1024 -> 512 blocks
  for (int k = 0; k < 16; ++k) {
    const _Float16* towH = towAllH + (size_t)k * 8192 * 64;

    // K1m: x=[sum|tow] @ MW1^T -> m1 (2-MFMA, packed B)
    gemm_m_kernel<<<G, B256, 0, stream>>>(sumH, 1024, towH, 64,
                                          1024, 1088, MW1p, Mb1, m1H, 1024);
    // K1h: x=[sum|tow] @ OW1^T -> h1 (1-MFMA, packed B)
    gemm_h_kernel<<<G, B256, 0, stream>>>(sumH, 1024, towH, 64, 1024, 1088,
                                          OW1p, Ob1, h1, 1024, nullptr, nullptr);
    // K2m: m1 @ MW2^T -> m2
    gemm_m_kernel<<<G, B256, 0, stream>>>(m1H, 1024, m1H, 1024,
                                          1024, 1024, MW2p, Mb2, m2H, 1024);
    // K2h: h1 @ OW2^T -> fused relu+dot(OW3) into sacc
    gemm_h_kernel<<<G, B256, 0, stream>>>(h1, 1024, h1, 1024, 1024, 1024,
                                          OW2p, Ob2, nullptr, 1024, OW3, sacc);
    // K3: m2 @ MW3^T -> summary (in-place: K1m/K1h already consumed it)
    gemm_m_kernel<<<G, B256, 0, stream>>>(m2H, 1024, m2H, 1024,
                                          1024, 1024, MW3p, Mb3, sumH, 1024);
    // pred + product accumulate + re-zero sacc
    pred_final_kernel<<<dim3(32), B256, 0, stream>>>(sacc, Ob3, out, k);
  }
}

// Round 13
// 2750.739 us; speedup vs baseline: 1.2388x; 1.2388x over previous
//
#include <hip/hip_runtime.h>
#include <cstdint>
#include <cstddef>

// BottomUpNet: N=8192 rows independent; K=16 sequential steps.
// R13: fix R12's exposed-latency regression. B-weights stay pre-packed in
// MFMA fragment order, but ALL 16 B-fragment loads of a k-iter are issued at
// the top of the iteration, BEFORE the A global_load_lds stream. B loads are
// then oldest in the vmcnt queue -> complete before the A-drain at the
// barrier; MFMA phase consumes them from VGPRs with zero exposed latency.
// (R12 evidence: VGPR_Count=56 -> compiler issued B loads per-kh on demand,
// ~200cyc L2 latency x4 per iter = +23k cyc/CU vs R11.)
// Register budget: B 64 + acc 64 + A frags/addr ~20 = ~150 < 170 cap @(256,3).
// m-chain 2 MFMAs (weights fp32-exact hi/lo), h-chain 1 MFMA. Bit-identical.

typedef _Float16 f16x8 __attribute__((ext_vector_type(8)));
typedef float f32x16 __attribute__((ext_vector_type(16)));

__device__ __forceinline__ void gload16(const void* g, void* l) {
  // async global->LDS, 16B/lane, LDS dest = wave-uniform base + lane*16
  __builtin_amdgcn_global_load_lds(
      (__attribute__((address_space(1))) void*)const_cast<void*>(g),
      (__attribute__((address_space(3))) void*)l,
      16, 0, 0);
}

// ---- m-GEMM: C = relu(A@B^T + bias); A fp16 hi via LDS; B packed hi/lo
// global-direct (2 MFMAs). Tile 128x128, BK=64, 256 thr (4 waves, 64x64 each).
__global__ __launch_bounds__(256, 3)
void gemm_m_kernel(const _Float16* __restrict__ AH0, int ldA0,
                   const _Float16* __restrict__ AH1, int ldA1,
                   int kcut, int Ktot,
                   const _Float16* __restrict__ PB,   // packed [n32][k16][2][512]
                   const float* __restrict__ bias,
                   _Float16* __restrict__ CH, int ldC)
{
  __shared__ _Float16 sAh[128 * 64];

  const int lane = threadIdx.x & 63;
  const int wave = threadIdx.x >> 6;
  const int wm = (wave >> 1) * 64, wn = (wave & 1) * 64;
  const int mBase = blockIdx.x * 128, nBase = blockIdx.y * 128;

  // A staging: 8 rows/chunk (128 B rows), 8 lanes/row; seg swizz = ^(row&7)
  const int lr = lane >> 3;
  const int lcs8 = ((lane & 7) ^ lr) * 8;
  const int l31 = lane & 31, l5 = lane >> 5;
  const int fswz = l31 & 7;

  const int Kt16 = Ktot >> 4;
  const int n32b = (nBase + wn) >> 5;
  const _Float16* pb0 = PB + ((size_t)(n32b)*Kt16) * 1024 + lane * 8;
  const _Float16* pb1 = PB + ((size_t)(n32b + 1) * Kt16) * 1024 + lane * 8;

  f32x16 acc[2][2];
#pragma unroll
  for (int i = 0; i < 2; ++i)
#pragma unroll
    for (int j = 0; j < 2; ++j)
      acc[i][j] = (f32x16)0.0f;

  for (int kt = 0; kt < Ktot; kt += 64) {
    // ---- issue ALL B loads for this k-iter FIRST (oldest in vmcnt queue)
    f16x8 bh[4][2], bl[4][2];
#pragma unroll
    for (int kh = 0; kh < 4; ++kh) {
      const size_t k16 = (size_t)((kt >> 4) + kh) * 1024;
      bh[kh][0] = *(const f16x8*)(pb0 + k16);
      bl[kh][0] = *(const f16x8*)(pb0 + k16 + 512);
      bh[kh][1] = *(const f16x8*)(pb1 + k16);
      bl[kh][1] = *(const f16x8*)(pb1 + k16 + 512);
    }

    // ---- then A staging (drained by the barrier; B completes even earlier)
    const _Float16* aH; int pA, kl;
    if (kt < kcut) { aH = AH0; pA = ldA0; kl = kt; }
    else           { aH = AH1; pA = ldA1; kl = kt - kcut; }
#pragma unroll
    for (int cc = 0; cc < 4; ++cc) {
      const int c = wave * 4 + cc;                  // chunk 0..15, 8 rows each
      const int arow = mBase + c * 8 + lr;
      gload16(aH + (size_t)arow * pA + kl + lcs8, &sAh[c * 512]);
    }
    __syncthreads();

#pragma unroll
    for (int kh = 0; kh < 4; ++kh) {                // four K=16 MFMAs per BK=64
      const int ko = ((kh * 2 + l5) ^ fswz) * 8;    // swizzled A seg (0..7)
      f16x8 ah[2];
#pragma unroll
      for (int i = 0; i < 2; ++i)
        ah[i] = *(const f16x8*)&sAh[(wm + i * 32 + l31) * 64 + ko];
#pragma unroll
      for (int i = 0; i < 2; ++i)
#pragma unroll
        for (int j = 0; j < 2; ++j) {
          acc[i][j] = __builtin_amdgcn_mfma_f32_32x32x16_f16(ah[i], bl[kh][j], acc[i][j], 0, 0, 0);
          acc[i][j] = __builtin_amdgcn_mfma_f32_32x32x16_f16(ah[i], bh[kh][j], acc[i][j], 0, 0, 0);
        }
    }
    __syncthreads();
  }

  float bv[2];
#pragma unroll
  for (int j = 0; j < 2; ++j) bv[j] = bias[nBase + wn + j * 32 + l31];
#pragma unroll
  for (int i = 0; i < 2; ++i)
#pragma unroll
    for (int j = 0; j < 2; ++j)
#pragma unroll
      for (int r = 0; r < 16; ++r) {
        const int row = mBase + wm + i * 32 + (r & 3) + 8 * (r >> 2) + 4 * l5;
        const int col = nBase + wn + j * 32 + l31;
        float v = fmaxf(acc[i][j][r] + bv[j], 0.0f);
        CH[(size_t)row * ldC + col] = (_Float16)v;
      }
}

// ---- h-GEMM (hi-only, 1 MFMA): C = relu(A@B^T + bias) fp16 out,
// or fused-pred mode (sacc != null): sacc[row] += sum_col relu(.)*w3[col]
__global__ __launch_bounds__(256, 3)
void gemm_h_kernel(const _Float16* __restrict__ A0, int ldA0,
                   const _Float16* __restrict__ A1, int ldA1,
                   int kcut, int Ktot,
                   const _Float16* __restrict__ PB,   // packed [n32][k16][512]
                   const float* __restrict__ bias,
                   _Float16* __restrict__ C, int ldC,
                   const float* __restrict__ w3, float* __restrict__ sacc)
{
  __shared__ _Float16 sAh[128 * 64];

  const int lane = threadIdx.x & 63;
  const int wave = threadIdx.x >> 6;
  const int wm = (wave >> 1) * 64, wn = (wave & 1) * 64;
  const int mBase = blockIdx.x * 128, nBase = blockIdx.y * 128;

  const int lr = lane >> 3;
  const int lcs8 = ((lane & 7) ^ lr) * 8;
  const int l31 = lane & 31, l5 = lane >> 5;
  const int fswz = l31 & 7;

  const int Kt16 = Ktot >> 4;
  const int n32b = (nBase + wn) >> 5;
  const _Float16* pb0 = PB + ((size_t)(n32b)*Kt16) * 512 + lane * 8;
  const _Float16* pb1 = PB + ((size_t)(n32b + 1) * Kt16) * 512 + lane * 8;

  f32x16 acc[2][2];
#pragma unroll
  for (int i = 0; i < 2; ++i)
#pragma unroll
    for (int j = 0; j < 2; ++j)
      acc[i][j] = (f32x16)0.0f;

  for (int kt = 0; kt < Ktot; kt += 64) {
    // ---- issue ALL B loads for this k-iter first
    f16x8 bh[4][2];
#pragma unroll
    for (int kh = 0; kh < 4; ++kh) {
      const size_t k16 = (size_t)((kt >> 4) + kh) * 512;
      bh[kh][0] = *(const f16x8*)(pb0 + k16);
      bh[kh][1] = *(const f16x8*)(pb1 + k16);
    }

    const _Float16* aH; int pA, kl;
    if (kt < kcut) { aH = A0; pA = ldA0; kl = kt; }
    else           { aH = A1; pA = ldA1; kl = kt - kcut; }
#pragma unroll
    for (int cc = 0; cc < 4; ++cc) {
      const int c = wave * 4 + cc;
      const int arow = mBase + c * 8 + lr;
      gload16(aH + (size_t)arow * pA + kl + lcs8, &sAh[c * 512]);
    }
    __syncthreads();

#pragma unroll
    for (int kh = 0; kh < 4; ++kh) {
      const int ko = ((kh * 2 + l5) ^ fswz) * 8;
      f16x8 ah[2];
#pragma unroll
      for (int i = 0; i < 2; ++i)
        ah[i] = *(const f16x8*)&sAh[(wm + i * 32 + l31) * 64 + ko];
#pragma unroll
      for (int i = 0; i < 2; ++i)
#pragma unroll
        for (int j = 0; j < 2; ++j)
          acc[i][j] = __builtin_amdgcn_mfma_f32_32x32x16_f16(ah[i], bh[kh][j], acc[i][j], 0, 0, 0);
    }
    __syncthreads();
  }

  float bv[2], w3v[2];
#pragma unroll
  for (int j = 0; j < 2; ++j) {
    const int col = nBase + wn + j * 32 + l31;
    bv[j] = bias[col];
    w3v[j] = sacc ? w3[col] : 0.0f;
  }

  if (sacc) {
#pragma unroll
    for (int i = 0; i < 2; ++i)
#pragma unroll
      for (int r = 0; r < 16; ++r) {
        float pr = 0.0f;
#pragma unroll
        for (int j = 0; j < 2; ++j)
          pr += fmaxf(acc[i][j][r] + bv[j], 0.0f) * w3v[j];
        pr += __shfl_xor(pr, 1);
        pr += __shfl_xor(pr, 2);
        pr += __shfl_xor(pr, 4);
        pr += __shfl_xor(pr, 8);
        pr += __shfl_xor(pr, 16);
        if (l31 == 0)
          atomicAdd(&sacc[mBase + wm + i * 32 + (r & 3) + 8 * (r >> 2) + 4 * l5], pr);
      }
  } else {
#pragma unroll
    for (int i = 0; i < 2; ++i)
#pragma unroll
      for (int j = 0; j < 2; ++j)
#pragma unroll
        for (int r = 0; r < 16; ++r) {
          const int row = mBase + wm + i * 32 + (r & 3) + 8 * (r >> 2) + 4 * l5;
          const int col = nBase + wn + j * 32 + l31;
          float v = fmaxf(acc[i][j][r] + bv[j], 0.0f);
          C[(size_t)row * ldC + col] = (_Float16)v;
        }
  }
}

// W (K x N fp32) -> packed B-fragment layout.
// tid -> (n32, k16, lane, e); col=n32*32+(lane&31), k=k16*16+(lane>>5)*8+e.
// withLo: chunk pair [hi 512][lo 512] (stride 1024), else hi only (512).
__global__ void wconv_pack_kernel(const float* __restrict__ W, int K, int N,
                                  _Float16* __restrict__ out, int withLo) {
  int tid = blockIdx.x * 256 + threadIdx.x;
  if (tid >= K * N) return;
  const int Kt16 = K >> 4;
  int e = tid & 7;
  int lane = (tid >> 3) & 63;
  int k16 = (tid >> 9) % Kt16;
  int n32 = (tid >> 9) / Kt16;
  int col = (n32 << 5) + (lane & 31);
  int k = (k16 << 4) + ((lane >> 5) << 3) + e;
  float v = W[(size_t)k * N + col];
  _Float16 h = (_Float16)v;
  size_t base = ((size_t)(n32 * Kt16 + k16)) * (withLo ? 1024 : 512) + lane * 8 + e;
  out[base] = h;
  if (withLo) out[base + 512] = (_Float16)(v - (float)h);
}

__global__ void init_summary_kernel(const float* __restrict__ agg,
                                    _Float16* __restrict__ sH,
                                    float* __restrict__ sacc) {
  int idx = blockIdx.x * 256 + threadIdx.x;   // 8192*1024
  sH[idx] = (_Float16)agg[idx & 1023];
  if (idx < 8192) sacc[idx] = 0.0f;
}

// towers [n][k][f] fp32 -> towAll [k][n][f] fp16 hi (all 16 slices)
__global__ void tow_conv_all_kernel(const float* __restrict__ towers,
                                    _Float16* __restrict__ oH) {
  size_t idx = (size_t)blockIdx.x * 256 + threadIdx.x;  // (k*8192+n)*64+f
  int f = idx & 63;
  int n = (int)((idx >> 6) & 8191);
  int k = (int)(idx >> 19);
  oH[idx] = (_Float16)towers[((size_t)n * 16 + k) * 64 + f];
}

// pred = sigmoid(sacc + Ob3); out *= pred; re-zero sacc for next step
__global__ void pred_final_kernel(float* __restrict__ sacc, const float* __restrict__ b3,
                                  float* __restrict__ out, int step) {
  int row = blockIdx.x * 256 + threadIdx.x;   // 8192
  float p = 1.0f / (1.0f + expf(-(sacc[row] + b3[0])));
  out[row] = (step == 0) ? p : out[row] * p;
  sacc[row] = 0.0f;
}

extern "C" void kernel_launch(void* const* d_in, const int* in_sizes, int n_in,
                              void* d_out, int out_size, void* d_ws, size_t ws_size,
                              hipStream_t stream) {
  const float* towers = (const float*)d_in[0];
  const float* agg    = (const float*)d_in[1];
  const float* MW1 = (const float*)d_in[2];
  const float* Mb1 = (const float*)d_in[3];
  const float* MW2 = (const float*)d_in[4];
  const float* Mb2 = (const float*)d_in[5];
  const float* MW3 = (const float*)d_in[6];
  const float* Mb3 = (const float*)d_in[7];
  const float* OW1 = (const float*)d_in[8];
  const float* Ob1 = (const float*)d_in[9];
  const float* OW2 = (const float*)d_in[10];
  const float* Ob2 = (const float*)d_in[11];
  const float* OW3 = (const float*)d_in[12];
  const float* Ob3 = (const float*)d_in[13];
  float* out = (float*)d_out;

  // ws layout (~102 MiB)
  _Float16* p = (_Float16*)d_ws;
  _Float16* MW1p = p; p += (size_t)32 * 68 * 1024;   // hi/lo pairs
  _Float16* OW1p = p; p += (size_t)32 * 68 * 512;    // hi only
  _Float16* MW2p = p; p += (size_t)32 * 64 * 1024;
  _Float16* OW2p = p; p += (size_t)32 * 64 * 512;
  _Float16* MW3p = p; p += (size_t)32 * 64 * 1024;
  _Float16* sumH = p; p += (size_t)8192 * 1024;
  _Float16* m1H  = p; p += (size_t)8192 * 1024;
  _Float16* h1   = p; p += (size_t)8192 * 1024;
  _Float16* m2H  = p; p += (size_t)8192 * 1024;
  _Float16* towAllH = p; p += (size_t)16 * 8192 * 64;
  float* sacc = (float*)p;

  // per-call setup: pack weights into fragment layout, convert towers, init
  {
    int tot = 1088 * 1024;
    wconv_pack_kernel<<<dim3((tot + 255) / 256), dim3(256), 0, stream>>>(MW1, 1088, 1024, MW1p, 1);
    wconv_pack_kernel<<<dim3((tot + 255) / 256), dim3(256), 0, stream>>>(OW1, 1088, 1024, OW1p, 0);
    tot = 1024 * 1024;
    wconv_pack_kernel<<<dim3((tot + 255) / 256), dim3(256), 0, stream>>>(MW2, 1024, 1024, MW2p, 1);
    wconv_pack_kernel<<<dim3((tot + 255) / 256), dim3(256), 0, stream>>>(OW2, 1024, 1024, OW2p, 0);
    wconv_pack_kernel<<<dim3((tot + 255) / 256), dim3(256), 0, stream>>>(MW3, 1024, 1024, MW3p, 1);
    init_summary_kernel<<<dim3(32768), dim3(256), 0, stream>>>(agg, sumH, sacc);
    tow_conv_all_kernel<<<dim3(32768), dim3(256), 0, stream>>>(towers, towAllH);
  }

  const dim3 G(64, 8), B256(256);   // 128x128 tiles over 8192x1024 -> 512 blocks
  for (int k = 0; k < 16; ++k) {
    const _Float16* towH = towAllH + (size_t)k * 8192 * 64;

    // K1m: x=[sum|tow] @ MW1^T -> m1 (2-MFMA, packed B)
    gemm_m_kernel<<<G, B256, 0, stream>>>(sumH, 1024, towH, 64,
                                          1024, 1088, MW1p, Mb1, m1H, 1024);
    // K1h: x=[sum|tow] @ OW1^T -> h1 (1-MFMA, packed B)
    gemm_h_kernel<<<G, B256, 0, stream>>>(sumH, 1024, towH, 64, 1024, 1088,
                                          OW1p, Ob1, h1, 1024, nullptr, nullptr);
    // K2m: m1 @ MW2^T -> m2
    gemm_m_kernel<<<G, B256, 0, stream>>>(m1H, 1024, m1H, 1024,
                                          1024, 1024, MW2p, Mb2, m2H, 1024);
    // K2h: h1 @ OW2^T -> fused relu+dot(OW3) into sacc
    gemm_h_kernel<<<G, B256, 0, stream>>>(h1, 1024, h1, 1024, 1024, 1024,
                                          OW2p, Ob2, nullptr, 1024, OW3, sacc);
    // K3: m2 @ MW3^T -> summary (in-place: K1m/K1h already consumed it)
    gemm_m_kernel<<<G, B256, 0, stream>>>(m2H, 1024, m2H, 1024,
                                          1024, 1024, MW3p, Mb3, sumH, 1024);
    // pred + product accumulate + re-zero sacc
    pred_final_kernel<<<dim3(32), B256, 0, stream>>>(sacc, Ob3, out, k);
  }
}